// Round 5
// baseline (209.919 us; speedup 1.0000x reference)
//
#include <hip/hip_runtime.h>
#include <hip/hip_bf16.h>
#include <math.h>

constexpr int N_   = 8192;
constexpr int D_   = 256;
constexpr int E_   = 131072;
constexpr int G_   = 16;
constexpr int MN_  = 512;
constexpr int H_   = 8;
constexpr int MAXG_= 512;

typedef __attribute__((ext_vector_type(8))) short short8v;   // 8 bf16 (4 VGPR)
typedef __attribute__((ext_vector_type(4))) float f32x4;     // MFMA C/D

// ---- bf16 helpers (RTNE via integer ops; inputs finite) ----
__device__ inline ushort f2bf(float f) {
    unsigned u = __float_as_uint(f);
    return (ushort)((u + 0x7FFFu + ((u >> 16) & 1u)) >> 16);
}
__device__ inline float bf2f(ushort h) { return __uint_as_float((unsigned)h << 16); }
__device__ inline unsigned cvt_pk_bf16(float lo, float hi) {
    unsigned r;
    asm("v_cvt_pk_bf16_f32 %0, %1, %2" : "=v"(r) : "v"(lo), "v"(hi));
    return r;
}

// ---------------- small index kernels ----------------
__global__ void k_deg(const int* __restrict__ src, int* __restrict__ deg) {
    int e = blockIdx.x * 256 + threadIdx.x;
    if (e < E_) atomicAdd(deg + src[e], 1);
}

// boundary detect on sorted batch: G uncontended writes total
__global__ void k_bounds(const int* __restrict__ batch, int* __restrict__ bstart) {
    int n = blockIdx.x * 256 + threadIdx.x;
    if (n >= N_) return;
    int g = batch[n];
    if (n == 0 || batch[n - 1] != g) bstart[g] = n;
}

// single-thread backward fill: starts/counts from bstart (empty graphs -> 0)
__global__ void k_starts(const int* __restrict__ bstart, int* __restrict__ starts,
                         int* __restrict__ counts) {
    if (threadIdx.x != 0 || blockIdx.x != 0) return;
    int next = N_;
    for (int g = G_ - 1; g >= 0; --g) {
        int b = bstart[g];
        int s = (b >= 0) ? b : next;
        starts[g] = s;
        counts[g] = next - s;
        next = s;
    }
}

// exclusive scan of deg over N nodes (single block, LDS Hillis-Steele)
__global__ void k_scan_deg(const int* __restrict__ deg, int* __restrict__ offs,
                           int* __restrict__ cursor) {
    __shared__ int sums[256];
    int t = threadIdx.x;
    int base = t * 32;
    int local[32];
    int s = 0;
#pragma unroll
    for (int k = 0; k < 32; ++k) { local[k] = deg[base + k]; s += local[k]; }
    sums[t] = s;
    __syncthreads();
    for (int off = 1; off < 256; off <<= 1) {
        int v = (t >= off) ? sums[t - off] : 0;
        __syncthreads();
        sums[t] += v;
        __syncthreads();
    }
    int acc = sums[t] - s;   // exclusive prefix for this thread's chunk
#pragma unroll
    for (int k = 0; k < 32; ++k) {
        offs[base + k] = acc;
        cursor[base + k] = acc;
        acc += local[k];
    }
}

__global__ void k_fill_csr(const int* __restrict__ src, int* __restrict__ cursor,
                           int* __restrict__ eids) {
    int e = blockIdx.x * 256 + threadIdx.x;
    if (e < E_) {
        int slot = atomicAdd(cursor + src[e], 1);
        eids[slot] = e;
    }
}

// ---------------- build dense batch (CSR gather fused), emit bf16 hi/lo ----------------
__global__ void k_build_dense(const float* __restrict__ nf, const float* __restrict__ cent,
                              const float* __restrict__ ef, const int* __restrict__ deg,
                              const int* __restrict__ offs, const int* __restrict__ eids,
                              const int* __restrict__ batch, const int* __restrict__ starts,
                              ushort* __restrict__ xh, ushort* __restrict__ xl) {
    int t  = blockIdx.x * 256 + threadIdx.x;
    int n  = t >> 6;
    int c4 = (t & 63) * 4;
    if (n >= N_) return;
    int g = batch[n];
    int p = n - starts[g];
    if (p >= MN_) return;
    int row = g * MN_ + p;
    int dn = deg[n];
    int dg = min(dn, MAXG_ - 1);
    float4 a = *(const float4*)(nf   + (size_t)n  * D_ + c4);
    float4 b = *(const float4*)(cent + (size_t)dg * D_ + c4);
    float4 o;
    o.x = a.x + b.x; o.y = a.y + b.y; o.z = a.z + b.z; o.w = a.w + b.w;
    int beg = offs[n], end = beg + dn;
    for (int idx = beg; idx < end; ++idx) {
        int e = eids[idx];
        float4 v = *(const float4*)(ef + (size_t)e * D_ + c4);
        o.x += v.x; o.y += v.y; o.z += v.z; o.w += v.w;
    }
    ushort4 hh, ll;
    hh.x = f2bf(o.x); ll.x = f2bf(o.x - bf2f(hh.x));
    hh.y = f2bf(o.y); ll.y = f2bf(o.y - bf2f(hh.y));
    hh.z = f2bf(o.z); ll.z = f2bf(o.z - bf2f(hh.z));
    hh.w = f2bf(o.w); ll.w = f2bf(o.w - bf2f(hh.w));
    *(ushort4*)(xh + (size_t)row * D_ + c4) = hh;
    *(ushort4*)(xl + (size_t)row * D_ + c4) = ll;
}

// ---------------- weight transpose + hi/lo split: W[256][ncols] -> Wt[ncols][256] ----------------
__global__ __launch_bounds__(256) void k_wt(const float* __restrict__ W, int ncols,
                                            ushort* __restrict__ wth, ushort* __restrict__ wtl) {
    __shared__ float tile[32][33];
    int c0 = blockIdx.x * 32, k0 = blockIdx.y * 32;
    int t = threadIdx.x;
    int tr = t >> 5, tc = t & 31;
#pragma unroll
    for (int i = 0; i < 4; ++i)
        tile[tr * 4 + i][tc] = W[(size_t)(k0 + tr * 4 + i) * ncols + c0 + tc];
    __syncthreads();
    int cr = t >> 3, kq = (t & 7) * 4;
    ushort4 hh, ll;
    float v;
    v = tile[kq + 0][cr]; hh.x = f2bf(v); ll.x = f2bf(v - bf2f(hh.x));
    v = tile[kq + 1][cr]; hh.y = f2bf(v); ll.y = f2bf(v - bf2f(hh.y));
    v = tile[kq + 2][cr]; hh.z = f2bf(v); ll.z = f2bf(v - bf2f(hh.z));
    v = tile[kq + 3][cr]; hh.w = f2bf(v); ll.w = f2bf(v - bf2f(hh.w));
    *(ushort4*)(wth + (size_t)(c0 + cr) * 256 + k0 + kq) = hh;
    *(ushort4*)(wtl + (size_t)(c0 + cr) * 256 + k0 + kq) = ll;
}

// ---------------- MFMA QKV GEMM: x[8192][256] @ W[256][768] (hi/lo compensated) ----------------
// Wave: 16 M-rows x 64 cols. Epilogue: Q,K -> hi/lo bf16; V -> bf16 transposed into vt.
__global__ __launch_bounds__(256) void k_gemm_qkv(
    const ushort* __restrict__ xh, const ushort* __restrict__ xl,
    const ushort* __restrict__ wth, const ushort* __restrict__ wtl,
    ushort* __restrict__ qh, ushort* __restrict__ qlo,
    ushort* __restrict__ kh, ushort* __restrict__ klo,
    ushort* __restrict__ vt) {
    int w = threadIdx.x >> 6, lane = threadIdx.x & 63;
    int l15 = lane & 15, quad = lane >> 4;
    int m0 = blockIdx.x * 64 + w * 16;
    int nc0 = blockIdx.y * 64;
    f32x4 acc[4] = {};
    const ushort* ah_p = xh + (size_t)(m0 + l15) * 256 + quad * 8;
    const ushort* al_p = xl + (size_t)(m0 + l15) * 256 + quad * 8;
    for (int kc = 0; kc < 256; kc += 32) {
        short8v ah = *(const short8v*)(ah_p + kc);
        short8v al = *(const short8v*)(al_p + kc);
#pragma unroll
        for (int c = 0; c < 4; ++c) {
            size_t bo = (size_t)(nc0 + c * 16 + l15) * 256 + kc + quad * 8;
            short8v bh = *(const short8v*)(wth + bo);
            short8v bl = *(const short8v*)(wtl + bo);
            acc[c] = __builtin_amdgcn_mfma_f32_16x16x32_bf16(al, bh, acc[c], 0, 0, 0);
            acc[c] = __builtin_amdgcn_mfma_f32_16x16x32_bf16(ah, bl, acc[c], 0, 0, 0);
            acc[c] = __builtin_amdgcn_mfma_f32_16x16x32_bf16(ah, bh, acc[c], 0, 0, 0);
        }
    }
    int seg = nc0 >> 8;          // 0:Q 1:K 2:V (64-col block stays in one segment)
    int g = m0 >> 9;
    int r0 = m0 + quad * 4;
#pragma unroll
    for (int c = 0; c < 4; ++c) {
        int col = nc0 + c * 16 + l15;
        if (seg == 0) {
#pragma unroll
            for (int r = 0; r < 4; ++r) {
                float v = acc[c][r];
                ushort hh = f2bf(v);
                qh [(size_t)(r0 + r) * 256 + col] = hh;
                qlo[(size_t)(r0 + r) * 256 + col] = f2bf(v - bf2f(hh));
            }
        } else if (seg == 1) {
            int cc = col - 256;
#pragma unroll
            for (int r = 0; r < 4; ++r) {
                float v = acc[c][r];
                ushort hh = f2bf(v);
                kh [(size_t)(r0 + r) * 256 + cc] = hh;
                klo[(size_t)(r0 + r) * 256 + cc] = f2bf(v - bf2f(hh));
            }
        } else {
            int cv = col - 512;
            int h = cv >> 5, d = cv & 31;
            int j0 = (m0 - g * 512) + quad * 4;
            ushort4 vv;
            vv.x = f2bf(acc[c][0]); vv.y = f2bf(acc[c][1]);
            vv.z = f2bf(acc[c][2]); vv.w = f2bf(acc[c][3]);
            *(ushort4*)(vt + ((size_t)((g * 8 + h) * 32 + d)) * 512 + j0) = vv;
        }
    }
}

// ---------------- MFMA flash attention (O out as bf16 hi/lo) ----------------
__global__ __launch_bounds__(256) void k_attn_mfma(
    const ushort* __restrict__ qh, const ushort* __restrict__ qlo,
    const ushort* __restrict__ kh, const ushort* __restrict__ klo,
    const ushort* __restrict__ vt,
    const int* __restrict__ dist, const float* __restrict__ dist_bias,
    const int* __restrict__ counts, ushort* __restrict__ oh, ushort* __restrict__ ol)
{
    int b  = blockIdx.x;
    int gh = b >> 3;                 // g*8 + h
    int g  = gh >> 3, h = gh & 7;
    int w    = threadIdx.x >> 6;
    int lane = threadIdx.x & 63;
    int ib   = (b & 7) * 64 + w * 16;
    int l15  = lane & 15, quad = lane >> 4;
    const float scale = 0.17677669529663687f;

    __shared__ float biasH[512];
    for (int idx = threadIdx.x; idx < 512; idx += 256) biasH[idx] = dist_bias[idx * 8 + h];
    __syncthreads();
    int cnt = counts[g];

    size_t qoff = ((size_t)(g * 512 + ib + l15)) * 256 + h * 32 + quad * 8;
    short8v qfh = *(const short8v*)(qh  + qoff);
    short8v qfl = *(const short8v*)(qlo + qoff);

    float m = -INFINITY, lsum = 0.f;
    f32x4 acc0 = {0.f, 0.f, 0.f, 0.f}, acc1 = {0.f, 0.f, 0.f, 0.f};

    const ushort* vbase = vt + ((size_t)gh * 32) * 512;
    const int* dbase = dist + ((size_t)(g * 512 + ib + l15)) * 512;
    size_t krowb = (size_t)(g * 512);

    for (int jb = 0; jb < 512; jb += 32) {
        float p[8];
        float mx = -INFINITY;
#pragma unroll
        for (int sub = 0; sub < 2; ++sub) {
            int j0 = jb + sub * 16;
            size_t koff = (krowb + j0 + l15) * 256 + h * 32 + quad * 8;
            short8v kfh = *(const short8v*)(kh  + koff);
            short8v kfl = *(const short8v*)(klo + koff);
            f32x4 c = {0.f, 0.f, 0.f, 0.f};
            c = __builtin_amdgcn_mfma_f32_16x16x32_bf16(kfl, qfh, c, 0, 0, 0);
            c = __builtin_amdgcn_mfma_f32_16x16x32_bf16(kfh, qfl, c, 0, 0, 0);
            c = __builtin_amdgcn_mfma_f32_16x16x32_bf16(kfh, qfh, c, 0, 0, 0);
            int4 d4 = *(const int4*)(dbase + j0 + quad * 4);
            const int* dr = (const int*)&d4;
#pragma unroll
            for (int r = 0; r < 4; ++r) {
                int dd = min(dr[r], MAXG_ - 1);
                float s = c[r] * scale + biasH[dd];
                bool valid = (j0 + quad * 4 + r) < cnt;
                s = valid ? s : -1e30f;
                p[sub * 4 + r] = s;
                mx = fmaxf(mx, s);
            }
        }
        mx = fmaxf(mx, __shfl_xor(mx, 16));
        mx = fmaxf(mx, __shfl_xor(mx, 32));
        float mnew = fmaxf(m, mx);
        float corr = __expf(m - mnew);
        m = mnew;
        float psum = 0.f;
#pragma unroll
        for (int u = 0; u < 8; ++u) {
            float pv = (p[u] > -1e29f) ? __expf(p[u] - m) : 0.f;
            p[u] = pv;
            psum += pv;
        }
        psum += __shfl_xor(psum, 16);
        psum += __shfl_xor(psum, 32);
        lsum = lsum * corr + psum;
#pragma unroll
        for (int r = 0; r < 4; ++r) {
            float cr = __shfl(corr, quad * 4 + r);
            acc0[r] *= cr; acc1[r] *= cr;
        }
        unsigned pk0A = cvt_pk_bf16(p[0], p[1]), pk1A = cvt_pk_bf16(p[2], p[3]);
        unsigned pk0B = cvt_pk_bf16(p[4], p[5]), pk1B = cvt_pk_bf16(p[6], p[7]);
        int srcA = l15 + 16 * (2 * (quad & 1));
        int srcB = srcA + 16;
        unsigned w0A = __shfl((int)pk0A, srcA), w1A = __shfl((int)pk1A, srcA);
        unsigned w2A = __shfl((int)pk0A, srcB), w3A = __shfl((int)pk1A, srcB);
        unsigned w0B = __shfl((int)pk0B, srcA), w1B = __shfl((int)pk1B, srcA);
        unsigned w2B = __shfl((int)pk0B, srcB), w3B = __shfl((int)pk1B, srcB);
        bool hiT = (quad >= 2);
        union { unsigned u[4]; short8v s; } pu;
        pu.u[0] = hiT ? w0B : w0A;
        pu.u[1] = hiT ? w1B : w1A;
        pu.u[2] = hiT ? w2B : w2A;
        pu.u[3] = hiT ? w3B : w3A;
        short8v pa = pu.s;
        short8v v0 = *(const short8v*)(vbase + (size_t)l15 * 512 + jb + quad * 8);
        short8v v1 = *(const short8v*)(vbase + (size_t)(l15 + 16) * 512 + jb + quad * 8);
        acc0 = __builtin_amdgcn_mfma_f32_16x16x32_bf16(pa, v0, acc0, 0, 0, 0);
        acc1 = __builtin_amdgcn_mfma_f32_16x16x32_bf16(pa, v1, acc1, 0, 0, 0);
    }
    float inv = lsum > 0.f ? 1.f / lsum : 0.f;
#pragma unroll
    for (int r = 0; r < 4; ++r) {
        float ir = __shfl(inv, quad * 4 + r);
        int i = ib + quad * 4 + r;
        size_t ob0 = ((size_t)(g * 512 + i)) * 256 + h * 32;
        float o0 = acc0[r] * ir, o1 = acc1[r] * ir;
        ushort h0 = f2bf(o0), h1 = f2bf(o1);
        oh[ob0 + l15]      = h0; ol[ob0 + l15]      = f2bf(o0 - bf2f(h0));
        oh[ob0 + 16 + l15] = h1; ol[ob0 + 16 + l15] = f2bf(o1 - bf2f(h1));
    }
}

// ---------------- MFMA proj GEMM + bias + ragged unpack + last-graph zeroing ----------------
__global__ __launch_bounds__(256) void k_gemm_proj(
    const ushort* __restrict__ oh, const ushort* __restrict__ ol,
    const ushort* __restrict__ woth, const ushort* __restrict__ wotl,
    const float* __restrict__ bo, const int* __restrict__ starts,
    const int* __restrict__ counts, float* __restrict__ out) {
    int w = threadIdx.x >> 6, lane = threadIdx.x & 63;
    int l15 = lane & 15, quad = lane >> 4;
    int m0 = blockIdx.x * 64 + w * 16;
    int nc0 = blockIdx.y * 64;
    f32x4 acc[4] = {};
    const ushort* ah_p = oh + (size_t)(m0 + l15) * 256 + quad * 8;
    const ushort* al_p = ol + (size_t)(m0 + l15) * 256 + quad * 8;
    for (int kc = 0; kc < 256; kc += 32) {
        short8v ah = *(const short8v*)(ah_p + kc);
        short8v al = *(const short8v*)(al_p + kc);
#pragma unroll
        for (int c = 0; c < 4; ++c) {
            size_t bof = (size_t)(nc0 + c * 16 + l15) * 256 + kc + quad * 8;
            short8v bh = *(const short8v*)(woth + bof);
            short8v bl = *(const short8v*)(wotl + bof);
            acc[c] = __builtin_amdgcn_mfma_f32_16x16x32_bf16(al, bh, acc[c], 0, 0, 0);
            acc[c] = __builtin_amdgcn_mfma_f32_16x16x32_bf16(ah, bl, acc[c], 0, 0, 0);
            acc[c] = __builtin_amdgcn_mfma_f32_16x16x32_bf16(ah, bh, acc[c], 0, 0, 0);
        }
    }
    int g = m0 >> 9;
    int cnt = counts[g], st = starts[g];
    bool lastg = (g == G_ - 1);
    int p0 = (m0 & 511) + quad * 4;
#pragma unroll
    for (int c = 0; c < 4; ++c) {
        int col = nc0 + c * 16 + l15;
        float bias = bo[col];
#pragma unroll
        for (int r = 0; r < 4; ++r) {
            int p = p0 + r;
            if (p < cnt) {
                int n = st + p;
                out[(size_t)n * 256 + col] = lastg ? 0.f : (acc[c][r] + bias);
            }
        }
    }
}

// ---------------- launch ----------------
extern "C" void kernel_launch(void* const* d_in, const int* in_sizes, int n_in,
                              void* d_out, int out_size, void* d_ws, size_t ws_size,
                              hipStream_t stream) {
    const float* node_feature = (const float*)d_in[0];
    const float* edge_feature = (const float*)d_in[1];
    const float* centrality   = (const float*)d_in[2];
    const float* dist_bias    = (const float*)d_in[3];
    const float* Wq           = (const float*)d_in[4];
    const float* Wkv          = (const float*)d_in[5];
    const float* Wo           = (const float*)d_in[6];
    const float* bo           = (const float*)d_in[7];
    const int*   edge_index   = (const int*)d_in[8];
    const int*   batch        = (const int*)d_in[9];
    const int*   dist         = (const int*)d_in[10];
    float* out = (float*)d_out;

    const size_t ND = (size_t)N_ * D_;       // 2M elements
    ushort* xh   = (ushort*)d_ws;            // bf16 buffers, 4 MB each
    ushort* xl   = xh  + ND;
    ushort* qh   = xl  + ND;
    ushort* qlo  = qh  + ND;
    ushort* kh   = qlo + ND;
    ushort* klo  = kh  + ND;
    ushort* vt   = klo + ND;
    ushort* oh   = vt  + ND;
    ushort* ol   = oh  + ND;
    ushort* wt_h = ol  + ND;                 // 768*256
    ushort* wt_l = wt_h + (size_t)768 * 256;
    ushort* wot_h= wt_l + (size_t)768 * 256; // 256*256
    ushort* wot_l= wot_h + (size_t)256 * 256;
    int* deg    = (int*)(wot_l + (size_t)256 * 256);
    int* bstart = deg + N_;
    int* counts = bstart + G_;
    int* starts = counts + G_;
    int* offs   = starts + G_;
    int* cursor = offs + N_;
    int* eids   = cursor + N_;

    hipMemsetAsync(deg, 0, (size_t)N_ * sizeof(int), stream);
    hipMemsetAsync(bstart, 0xFF, (size_t)G_ * sizeof(int), stream);  // -1

    const int* src = edge_index;  // row 0 of (2, E)

    k_deg<<<E_ / 256, 256, 0, stream>>>(src, deg);
    k_bounds<<<N_ / 256, 256, 0, stream>>>(batch, bstart);
    k_starts<<<1, 64, 0, stream>>>(bstart, starts, counts);
    k_scan_deg<<<1, 256, 0, stream>>>(deg, offs, cursor);
    k_fill_csr<<<E_ / 256, 256, 0, stream>>>(src, cursor, eids);
    // weights: transpose + hi/lo split (Wq|Wkv concat into wt, Wo into wot)
    k_wt<<<dim3(8, 8),  256, 0, stream>>>(Wq,  256, wt_h,              wt_l);
    k_wt<<<dim3(16, 8), 256, 0, stream>>>(Wkv, 512, wt_h + 256 * 256,  wt_l + 256 * 256);
    k_wt<<<dim3(8, 8),  256, 0, stream>>>(Wo,  256, wot_h,             wot_l);
    k_build_dense<<<(N_ * 64) / 256, 256, 0, stream>>>(node_feature, centrality, edge_feature,
                                                       deg, offs, eids, batch, starts, xh, xl);
    k_gemm_qkv<<<dim3(128, 12), 256, 0, stream>>>(xh, xl, wt_h, wt_l,
                                                  qh, qlo, kh, klo, vt);
    k_attn_mfma<<<G_ * H_ * 8, 256, 0, stream>>>(qh, qlo, kh, klo, vt,
                                                 dist, dist_bias, counts, oh, ol);
    k_gemm_proj<<<dim3(128, 4), 256, 0, stream>>>(oh, ol, wot_h, wot_l,
                                                  bo, starts, counts, out);
}

// Round 6
// 180.255 us; speedup vs baseline: 1.1646x; 1.1646x over previous
//
#include <hip/hip_runtime.h>
#include <hip/hip_bf16.h>
#include <math.h>

constexpr int N_   = 8192;
constexpr int D_   = 256;
constexpr int E_   = 131072;
constexpr int G_   = 16;
constexpr int MN_  = 512;
constexpr int H_   = 8;
constexpr int MAXG_= 512;

typedef __attribute__((ext_vector_type(8))) short short8v;   // 8 bf16 (4 VGPR)
typedef __attribute__((ext_vector_type(4))) float f32x4;     // MFMA C/D

// ---- bf16 helpers (RTNE via integer ops; inputs finite) ----
__device__ inline ushort f2bf(float f) {
    unsigned u = __float_as_uint(f);
    return (ushort)((u + 0x7FFFu + ((u >> 16) & 1u)) >> 16);
}
__device__ inline float bf2f(ushort h) { return __uint_as_float((unsigned)h << 16); }
__device__ inline unsigned cvt_pk_bf16(float lo, float hi) {
    unsigned r;
    asm("v_cvt_pk_bf16_f32 %0, %1, %2" : "=v"(r) : "v"(lo), "v"(hi));
    return r;
}

// ---------------- weight transpose + hi/lo split (device helper) ----------------
__device__ void wt_dev(const float* __restrict__ W, int ncols,
                       ushort* __restrict__ wth, ushort* __restrict__ wtl,
                       int bx, int by) {
    __shared__ float tile[32][33];
    int c0 = bx * 32, k0 = by * 32;
    int t = threadIdx.x;
    int tr = t >> 5, tc = t & 31;
#pragma unroll
    for (int i = 0; i < 4; ++i)
        tile[tr * 4 + i][tc] = W[(size_t)(k0 + tr * 4 + i) * ncols + c0 + tc];
    __syncthreads();
    int cr = t >> 3, kq = (t & 7) * 4;
    ushort4 hh, ll;
    float v;
    v = tile[kq + 0][cr]; hh.x = f2bf(v); ll.x = f2bf(v - bf2f(hh.x));
    v = tile[kq + 1][cr]; hh.y = f2bf(v); ll.y = f2bf(v - bf2f(hh.y));
    v = tile[kq + 2][cr]; hh.z = f2bf(v); ll.z = f2bf(v - bf2f(hh.z));
    v = tile[kq + 3][cr]; hh.w = f2bf(v); ll.w = f2bf(v - bf2f(hh.w));
    *(ushort4*)(wth + (size_t)(c0 + cr) * 256 + k0 + kq) = hh;
    *(ushort4*)(wtl + (size_t)(c0 + cr) * 256 + k0 + kq) = ll;
}

// ---------------- prep1: deg atomics + batch bounds + 3 weight transposes ----------------
// blockIdx: [0,512) deg over E ; [512,544) bounds over N ; [544,800) weights
__global__ __launch_bounds__(256) void k_prep1(
    const int* __restrict__ src, int* __restrict__ deg,
    const int* __restrict__ batch, int* __restrict__ bstart,
    const float* __restrict__ Wq, const float* __restrict__ Wkv,
    const float* __restrict__ Wo,
    ushort* __restrict__ wt_h, ushort* __restrict__ wt_l,
    ushort* __restrict__ wot_h, ushort* __restrict__ wot_l) {
    int bid = blockIdx.x;
    if (bid < 512) {
        int e = bid * 256 + threadIdx.x;
        atomicAdd(deg + src[e], 1);
    } else if (bid < 544) {
        int n = (bid - 512) * 256 + threadIdx.x;
        int g = batch[n];
        if (n == 0 || batch[n - 1] != g) bstart[g] = n;
    } else {
        int wid = bid - 544;
        if (wid < 64)        wt_dev(Wq,  256, wt_h, wt_l, wid & 7, wid >> 3);
        else if (wid < 192)  wt_dev(Wkv, 512, wt_h + 256 * 256, wt_l + 256 * 256,
                                    (wid - 64) & 15, (wid - 64) >> 4);
        else                 wt_dev(Wo,  256, wot_h, wot_l, (wid - 192) & 7, (wid - 192) >> 3);
    }
}

// ---------------- prep2: starts/counts backward-fill + exclusive deg scan ----------------
__global__ void k_prep2(const int* __restrict__ bstart, int* __restrict__ starts,
                        int* __restrict__ counts, const int* __restrict__ deg,
                        int* __restrict__ offs, int* __restrict__ cursor) {
    int t = threadIdx.x;
    if (t == 0) {
        int next = N_;
        for (int g = G_ - 1; g >= 0; --g) {
            int b = bstart[g];
            int s = (b >= 0) ? b : next;
            starts[g] = s;
            counts[g] = next - s;
            next = s;
        }
    }
    __shared__ int sums[256];
    int base = t * 32;
    int local[32];
    int s = 0;
#pragma unroll
    for (int k = 0; k < 32; ++k) { local[k] = deg[base + k]; s += local[k]; }
    sums[t] = s;
    __syncthreads();
    for (int off = 1; off < 256; off <<= 1) {
        int v = (t >= off) ? sums[t - off] : 0;
        __syncthreads();
        sums[t] += v;
        __syncthreads();
    }
    int acc = sums[t] - s;
#pragma unroll
    for (int k = 0; k < 32; ++k) {
        offs[base + k] = acc;
        cursor[base + k] = acc;
        acc += local[k];
    }
}

__global__ void k_fill_csr(const int* __restrict__ src, int* __restrict__ cursor,
                           int* __restrict__ eids) {
    int e = blockIdx.x * 256 + threadIdx.x;
    if (e < E_) {
        int slot = atomicAdd(cursor + src[e], 1);
        eids[slot] = e;
    }
}

// ---------------- build dense batch (CSR gather fused), emit bf16 hi/lo ----------------
__global__ void k_build_dense(const float* __restrict__ nf, const float* __restrict__ cent,
                              const float* __restrict__ ef, const int* __restrict__ deg,
                              const int* __restrict__ offs, const int* __restrict__ eids,
                              const int* __restrict__ batch, const int* __restrict__ starts,
                              ushort* __restrict__ xh, ushort* __restrict__ xl) {
    int t  = blockIdx.x * 256 + threadIdx.x;
    int n  = t >> 6;
    int c4 = (t & 63) * 4;
    if (n >= N_) return;
    int g = batch[n];
    int p = n - starts[g];
    if (p >= MN_) return;
    int row = g * MN_ + p;
    int dn = deg[n];
    int dg = min(dn, MAXG_ - 1);
    float4 a = *(const float4*)(nf   + (size_t)n  * D_ + c4);
    float4 b = *(const float4*)(cent + (size_t)dg * D_ + c4);
    float4 o;
    o.x = a.x + b.x; o.y = a.y + b.y; o.z = a.z + b.z; o.w = a.w + b.w;
    int beg = offs[n], end = beg + dn;
    for (int idx = beg; idx < end; ++idx) {
        int e = eids[idx];
        float4 v = *(const float4*)(ef + (size_t)e * D_ + c4);
        o.x += v.x; o.y += v.y; o.z += v.z; o.w += v.w;
    }
    ushort4 hh, ll;
    hh.x = f2bf(o.x); ll.x = f2bf(o.x - bf2f(hh.x));
    hh.y = f2bf(o.y); ll.y = f2bf(o.y - bf2f(hh.y));
    hh.z = f2bf(o.z); ll.z = f2bf(o.z - bf2f(hh.z));
    hh.w = f2bf(o.w); ll.w = f2bf(o.w - bf2f(hh.w));
    *(ushort4*)(xh + (size_t)row * D_ + c4) = hh;
    *(ushort4*)(xl + (size_t)row * D_ + c4) = ll;
}

// ---------------- MFMA QKV GEMM: x[8192][256] @ W[256][768] (hi/lo compensated) ----------------
__global__ __launch_bounds__(256) void k_gemm_qkv(
    const ushort* __restrict__ xh, const ushort* __restrict__ xl,
    const ushort* __restrict__ wth, const ushort* __restrict__ wtl,
    ushort* __restrict__ qh, ushort* __restrict__ qlo,
    ushort* __restrict__ kh, ushort* __restrict__ klo,
    ushort* __restrict__ vt) {
    int w = threadIdx.x >> 6, lane = threadIdx.x & 63;
    int l15 = lane & 15, quad = lane >> 4;
    int m0 = blockIdx.x * 64 + w * 16;
    int nc0 = blockIdx.y * 64;
    f32x4 acc[4] = {};
    const ushort* ah_p = xh + (size_t)(m0 + l15) * 256 + quad * 8;
    const ushort* al_p = xl + (size_t)(m0 + l15) * 256 + quad * 8;
    for (int kc = 0; kc < 256; kc += 32) {
        short8v ah = *(const short8v*)(ah_p + kc);
        short8v al = *(const short8v*)(al_p + kc);
#pragma unroll
        for (int c = 0; c < 4; ++c) {
            size_t bo = (size_t)(nc0 + c * 16 + l15) * 256 + kc + quad * 8;
            short8v bh = *(const short8v*)(wth + bo);
            short8v bl = *(const short8v*)(wtl + bo);
            acc[c] = __builtin_amdgcn_mfma_f32_16x16x32_bf16(al, bh, acc[c], 0, 0, 0);
            acc[c] = __builtin_amdgcn_mfma_f32_16x16x32_bf16(ah, bl, acc[c], 0, 0, 0);
            acc[c] = __builtin_amdgcn_mfma_f32_16x16x32_bf16(ah, bh, acc[c], 0, 0, 0);
        }
    }
    int seg = nc0 >> 8;          // 0:Q 1:K 2:V
    int g = m0 >> 9;
    int r0 = m0 + quad * 4;
#pragma unroll
    for (int c = 0; c < 4; ++c) {
        int col = nc0 + c * 16 + l15;
        if (seg == 0) {
#pragma unroll
            for (int r = 0; r < 4; ++r) {
                float v = acc[c][r];
                ushort hh = f2bf(v);
                qh [(size_t)(r0 + r) * 256 + col] = hh;
                qlo[(size_t)(r0 + r) * 256 + col] = f2bf(v - bf2f(hh));
            }
        } else if (seg == 1) {
            int cc = col - 256;
#pragma unroll
            for (int r = 0; r < 4; ++r) {
                float v = acc[c][r];
                ushort hh = f2bf(v);
                kh [(size_t)(r0 + r) * 256 + cc] = hh;
                klo[(size_t)(r0 + r) * 256 + cc] = f2bf(v - bf2f(hh));
            }
        } else {
            int cv = col - 512;
            int h = cv >> 5, d = cv & 31;
            int j0 = (m0 - g * 512) + quad * 4;
            ushort4 vv;
            vv.x = f2bf(acc[c][0]); vv.y = f2bf(acc[c][1]);
            vv.z = f2bf(acc[c][2]); vv.w = f2bf(acc[c][3]);
            *(ushort4*)(vt + ((size_t)((g * 8 + h) * 32 + d)) * 512 + j0) = vv;
        }
    }
}

// ---------------- fused MFMA attention (8 heads/block) + output projection + unpack ----------------
// Block: 512 threads = 8 waves; wave w = head w; one (g, 16-row i-tile) per block.
// dist staged once in LDS (shared across heads); after attention the dist LDS
// region is reused to stage O (bf16 hi/lo) for the in-block Wo projection.
__global__ __launch_bounds__(512) void k_attn_fused(
    const ushort* __restrict__ qh, const ushort* __restrict__ qlo,
    const ushort* __restrict__ kh, const ushort* __restrict__ klo,
    const ushort* __restrict__ vt,
    const int* __restrict__ dist, const float* __restrict__ dist_bias,
    const int* __restrict__ starts, const int* __restrict__ counts,
    const ushort* __restrict__ woth, const ushort* __restrict__ wotl,
    const float* __restrict__ bo, float* __restrict__ out)
{
    __shared__ int   dist_lds[16][516];   // 33 KB; reused for O staging after attn
    __shared__ float biasH[8][516];       // 16.5 KB (padded stride vs bank conflicts)

    int b  = blockIdx.x;
    int g  = b >> 5;
    int ib = (b & 31) * 16;
    int w    = threadIdx.x >> 6;          // = head
    int lane = threadIdx.x & 63;
    int l15  = lane & 15, quad = lane >> 4;
    int h = w;
    const float scale = 0.17677669529663687f;

    // stage bias table (all 512x8 entries, coalesced)
    for (int idx = threadIdx.x; idx < 4096; idx += 512)
        biasH[idx & 7][idx >> 3] = dist_bias[idx];
    // stage dist rows [ib, ib+16) once for all 8 heads
    {
        int r = threadIdx.x >> 5, c0 = (threadIdx.x & 31) * 16;
        const int* drow = dist + ((size_t)(g * 512 + ib + r)) * 512 + c0;
        int4 d0 = *(const int4*)(drow + 0);
        int4 d1 = *(const int4*)(drow + 4);
        int4 d2 = *(const int4*)(drow + 8);
        int4 d3 = *(const int4*)(drow + 12);
        *(int4*)&dist_lds[r][c0 + 0]  = d0;
        *(int4*)&dist_lds[r][c0 + 4]  = d1;
        *(int4*)&dist_lds[r][c0 + 8]  = d2;
        *(int4*)&dist_lds[r][c0 + 12] = d3;
    }
    __syncthreads();
    int cnt = counts[g];

    size_t qoff = ((size_t)(g * 512 + ib + l15)) * 256 + h * 32 + quad * 8;
    short8v qfh = *(const short8v*)(qh  + qoff);
    short8v qfl = *(const short8v*)(qlo + qoff);

    float m = -INFINITY, lsum = 0.f;
    f32x4 acc0 = {0.f, 0.f, 0.f, 0.f}, acc1 = {0.f, 0.f, 0.f, 0.f};

    const ushort* vbase = vt + ((size_t)((g * 8 + h) * 32)) * 512;
    size_t krowb = (size_t)(g * 512);

    for (int jb = 0; jb < 512; jb += 32) {
        float p[8];
        float mx = -INFINITY;
#pragma unroll
        for (int sub = 0; sub < 2; ++sub) {
            int j0 = jb + sub * 16;
            size_t koff = (krowb + j0 + l15) * 256 + h * 32 + quad * 8;
            short8v kfh = *(const short8v*)(kh  + koff);
            short8v kfl = *(const short8v*)(klo + koff);
            f32x4 c = {0.f, 0.f, 0.f, 0.f};
            c = __builtin_amdgcn_mfma_f32_16x16x32_bf16(kfl, qfh, c, 0, 0, 0);
            c = __builtin_amdgcn_mfma_f32_16x16x32_bf16(kfh, qfl, c, 0, 0, 0);
            c = __builtin_amdgcn_mfma_f32_16x16x32_bf16(kfh, qfh, c, 0, 0, 0);
            int4 d4 = *(const int4*)&dist_lds[l15][j0 + quad * 4];
            const int* dr = (const int*)&d4;
#pragma unroll
            for (int r = 0; r < 4; ++r) {
                int dd = min(dr[r], MAXG_ - 1);
                float s = c[r] * scale + biasH[h][dd];
                bool valid = (j0 + quad * 4 + r) < cnt;
                s = valid ? s : -1e30f;
                p[sub * 4 + r] = s;
                mx = fmaxf(mx, s);
            }
        }
        mx = fmaxf(mx, __shfl_xor(mx, 16));
        mx = fmaxf(mx, __shfl_xor(mx, 32));
        float mnew = fmaxf(m, mx);
        float corr = __expf(m - mnew);
        m = mnew;
        float psum = 0.f;
#pragma unroll
        for (int u = 0; u < 8; ++u) {
            float pv = (p[u] > -1e29f) ? __expf(p[u] - m) : 0.f;
            p[u] = pv;
            psum += pv;
        }
        psum += __shfl_xor(psum, 16);
        psum += __shfl_xor(psum, 32);
        lsum = lsum * corr + psum;
#pragma unroll
        for (int r = 0; r < 4; ++r) {
            float cr = __shfl(corr, quad * 4 + r);
            acc0[r] *= cr; acc1[r] *= cr;
        }
        unsigned pk0A = cvt_pk_bf16(p[0], p[1]), pk1A = cvt_pk_bf16(p[2], p[3]);
        unsigned pk0B = cvt_pk_bf16(p[4], p[5]), pk1B = cvt_pk_bf16(p[6], p[7]);
        int srcA = l15 + 16 * (2 * (quad & 1));
        int srcB = srcA + 16;
        unsigned w0A = __shfl((int)pk0A, srcA), w1A = __shfl((int)pk1A, srcA);
        unsigned w2A = __shfl((int)pk0A, srcB), w3A = __shfl((int)pk1A, srcB);
        unsigned w0B = __shfl((int)pk0B, srcA), w1B = __shfl((int)pk1B, srcA);
        unsigned w2B = __shfl((int)pk0B, srcB), w3B = __shfl((int)pk1B, srcB);
        bool hiT = (quad >= 2);
        union { unsigned u[4]; short8v s; } pu;
        pu.u[0] = hiT ? w0B : w0A;
        pu.u[1] = hiT ? w1B : w1A;
        pu.u[2] = hiT ? w2B : w2A;
        pu.u[3] = hiT ? w3B : w3A;
        short8v pa = pu.s;
        short8v v0 = *(const short8v*)(vbase + (size_t)l15 * 512 + jb + quad * 8);
        short8v v1 = *(const short8v*)(vbase + (size_t)(l15 + 16) * 512 + jb + quad * 8);
        acc0 = __builtin_amdgcn_mfma_f32_16x16x32_bf16(pa, v0, acc0, 0, 0, 0);
        acc1 = __builtin_amdgcn_mfma_f32_16x16x32_bf16(pa, v1, acc1, 0, 0, 0);
    }
    float inv = lsum > 0.f ? 1.f / lsum : 0.f;

    // ---- stage O (bf16 hi/lo) into retired dist LDS; then in-block projection ----
    __syncthreads();   // all waves done with dist_lds
    ushort* oh_lds = (ushort*)&dist_lds[0][0];     // [16][264]
    ushort* ol_lds = oh_lds + 16 * 264;            // 16.9 KB total, fits in 33 KB
#pragma unroll
    for (int r = 0; r < 4; ++r) {
        float ir = __shfl(inv, quad * 4 + r);
        int i = quad * 4 + r;
        float o0 = acc0[r] * ir, o1 = acc1[r] * ir;
        ushort h0 = f2bf(o0), h1 = f2bf(o1);
        oh_lds[i * 264 + h * 32 + l15]      = h0;
        ol_lds[i * 264 + h * 32 + l15]      = f2bf(o0 - bf2f(h0));
        oh_lds[i * 264 + h * 32 + 16 + l15] = h1;
        ol_lds[i * 264 + h * 32 + 16 + l15] = f2bf(o1 - bf2f(h1));
    }
    __syncthreads();

    // wave w computes out cols [w*32, w*32+32) for the 16 rows
    f32x4 pacc[2] = {};
    for (int kc = 0; kc < 256; kc += 32) {
        short8v ah = *(const short8v*)(oh_lds + l15 * 264 + kc + quad * 8);
        short8v al = *(const short8v*)(ol_lds + l15 * 264 + kc + quad * 8);
#pragma unroll
        for (int cc = 0; cc < 2; ++cc) {
            int col = w * 32 + cc * 16 + l15;
            size_t bof = (size_t)col * 256 + kc + quad * 8;
            short8v bh = *(const short8v*)(woth + bof);
            short8v bl = *(const short8v*)(wotl + bof);
            pacc[cc] = __builtin_amdgcn_mfma_f32_16x16x32_bf16(al, bh, pacc[cc], 0, 0, 0);
            pacc[cc] = __builtin_amdgcn_mfma_f32_16x16x32_bf16(ah, bl, pacc[cc], 0, 0, 0);
            pacc[cc] = __builtin_amdgcn_mfma_f32_16x16x32_bf16(ah, bh, pacc[cc], 0, 0, 0);
        }
    }
    int st = starts[g];
    bool lastg = (g == G_ - 1);
#pragma unroll
    for (int cc = 0; cc < 2; ++cc) {
        int col = w * 32 + cc * 16 + l15;
        float bias = bo[col];
#pragma unroll
        for (int r = 0; r < 4; ++r) {
            int p = ib + quad * 4 + r;
            if (p < cnt)
                out[(size_t)(st + p) * 256 + col] = lastg ? 0.f : (pacc[cc][r] + bias);
        }
    }
}

// ---------------- launch ----------------
extern "C" void kernel_launch(void* const* d_in, const int* in_sizes, int n_in,
                              void* d_out, int out_size, void* d_ws, size_t ws_size,
                              hipStream_t stream) {
    const float* node_feature = (const float*)d_in[0];
    const float* edge_feature = (const float*)d_in[1];
    const float* centrality   = (const float*)d_in[2];
    const float* dist_bias    = (const float*)d_in[3];
    const float* Wq           = (const float*)d_in[4];
    const float* Wkv          = (const float*)d_in[5];
    const float* Wo           = (const float*)d_in[6];
    const float* bo           = (const float*)d_in[7];
    const int*   edge_index   = (const int*)d_in[8];
    const int*   batch        = (const int*)d_in[9];
    const int*   dist         = (const int*)d_in[10];
    float* out = (float*)d_out;

    const size_t ND = (size_t)N_ * D_;       // 2M elements
    ushort* xh   = (ushort*)d_ws;            // bf16 buffers, 4 MB each
    ushort* xl   = xh  + ND;
    ushort* qh   = xl  + ND;
    ushort* qlo  = qh  + ND;
    ushort* kh   = qlo + ND;
    ushort* klo  = kh  + ND;
    ushort* vt   = klo + ND;
    ushort* wt_h = vt  + ND;                 // 768*256
    ushort* wt_l = wt_h + (size_t)768 * 256;
    ushort* wot_h= wt_l + (size_t)768 * 256; // 256*256
    ushort* wot_l= wot_h + (size_t)256 * 256;
    int* deg    = (int*)(wot_l + (size_t)256 * 256);
    int* bstart = deg + N_;
    int* counts = bstart + G_;
    int* starts = counts + G_;
    int* offs   = starts + G_;
    int* cursor = offs + N_;
    int* eids   = cursor + N_;

    hipMemsetAsync(deg, 0, (size_t)N_ * sizeof(int), stream);
    hipMemsetAsync(bstart, 0xFF, (size_t)G_ * sizeof(int), stream);  // -1

    const int* src = edge_index;  // row 0 of (2, E)

    k_prep1<<<800, 256, 0, stream>>>(src, deg, batch, bstart, Wq, Wkv, Wo,
                                     wt_h, wt_l, wot_h, wot_l);
    k_prep2<<<1, 256, 0, stream>>>(bstart, starts, counts, deg, offs, cursor);
    k_fill_csr<<<E_ / 256, 256, 0, stream>>>(src, cursor, eids);
    k_build_dense<<<(N_ * 64) / 256, 256, 0, stream>>>(node_feature, centrality, edge_feature,
                                                       deg, offs, eids, batch, starts, xh, xl);
    k_gemm_qkv<<<dim3(128, 12), 256, 0, stream>>>(xh, xl, wt_h, wt_l,
                                                  qh, qlo, kh, klo, vt);
    k_attn_fused<<<512, 512, 0, stream>>>(qh, qlo, kh, klo, vt, dist, dist_bias,
                                          starts, counts, wot_h, wot_l, bo, out);
}